// Round 1
// baseline (349.083 us; speedup 1.0000x reference)
//
#include <hip/hip_runtime.h>

#define BB 128
#define TT 512
#define CC 128

// ---------------------------------------------------------------------------
// Kernel 1: real path score = emission + transition, accumulated NEGATED into
// out[b] via atomicAdd (out zeroed beforehand by hipMemsetAsync).
// Grid: (B, 8) blocks x 256 threads. Each wave handles 16 consecutive t's
// (plus one overlap row for the boundary transition pair).
// ---------------------------------------------------------------------------
__global__ __launch_bounds__(256) void crf_real_path(
    const float* __restrict__ y_true, const float* __restrict__ y_pred,
    const float* __restrict__ mask, const float* __restrict__ trans,
    float* __restrict__ out)
{
    const int b    = blockIdx.x;
    const int tid  = threadIdx.x;
    const int lane = tid & 63;
    const int w    = tid >> 6;
    const int seg  = blockIdx.y * 4 + w;   // 0..31
    const int ts   = seg * 16;
    const int te   = min(ts + 16, TT - 1); // inclusive: extra row for boundary pair

    const float* yt_b = y_true + (size_t)b * TT * CC;
    const float* yp_b = y_pred + (size_t)b * TT * CC;
    const float* m_b  = mask + (size_t)b * TT;

    float em = 0.f, tr = 0.f;
    int lprev = 0; float mprev = 0.f;
    for (int t = ts; t <= te; ++t) {
        const float* ytr = yt_b + t * CC;
        const float* ypr = yp_b + t * CC;
        float yt0 = ytr[lane], yt1 = ytr[lane + 64];
        float yp0 = ypr[lane], yp1 = ypr[lane + 64];
        float m = m_b[t];
        unsigned long long b0 = __ballot(yt0 > 0.5f);
        unsigned long long b1 = __ballot(yt1 > 0.5f);
        int l = b0 ? (__ffsll(b0) - 1) : (64 + __ffsll(b1) - 1);
        float v0 = __shfl(yp0, l & 63);
        float v1 = __shfl(yp1, l & 63);
        float v  = (l < 64) ? v0 : v1;
        if (lane == 0) {
            if (t < ts + 16) em += m * m * v;                 // emission (masked^2)
            if (t > ts)      tr += mprev * m * trans[lprev * CC + l];
        }
        lprev = l; mprev = m;
    }
    if (lane == 0) atomicAdd(&out[b], -(em + tr));
}

// ---------------------------------------------------------------------------
// Kernel 2: forward scan in LINEAR space with periodic renormalization.
// One block per batch, 512 threads: thread (j = tid>>2, c4 = tid&3) owns
// E[i][j] for i in [c4*32, c4*32+32) in 32 fp32 registers.
// State vector (128 floats) double-buffered in LDS with an XOR-rotate bank
// swizzle so the 4 c4-groups of a wave hit disjoint bank quads (no conflicts).
// Renorm (divide by max, accumulate log) every 4 steps; renorm scale applied
// lazily ("pending") at the next state write.
// ---------------------------------------------------------------------------
__global__ __launch_bounds__(512) void crf_forward(
    const float* __restrict__ y_pred, const float* __restrict__ mask,
    const float* __restrict__ trans, float* __restrict__ out)
{
    __shared__ __align__(16) float pbuf[2 * CC];  // double-buffered state (swizzled)
    __shared__ float red_s;

    const int b   = blockIdx.x;
    const int tid = threadIdx.x;
    const int j   = tid >> 2;   // 0..127 output column
    const int c4  = tid & 3;    // i-chunk

    // E = exp(trans) in registers; logical element k -> i = c4*32 + k, col j.
    // (scattered 4B reads: 4 rows x 64B per instr, trans is 64KB and L2/L3-hot)
    float Ereg[32];
    #pragma unroll
    for (int k = 0; k < 32; ++k)
        Ereg[k] = __expf(trans[(c4 * 32 + k) * CC + j]);

    const float* yp_b = y_pred + (size_t)b * TT * CC;
    const float* m_b  = mask + (size_t)b * TT;

    // Physical swizzle: each 32-word block rotated by 8*blockIdx words.
    // Reader (c4,k) then naturally hits bank quad (4k + 8*c4)&31 -> the four
    // c4 groups of a wave use disjoint banks for every static k.
    const float4* pp[8];
    #pragma unroll
    for (int k = 0; k < 8; ++k) {
        int pc = c4 * 8 + ((k + 2 * c4) & 7);     // physical float4 chunk
        pp[k] = (const float4*)pbuf + pc;
    }
    int pj = (j & ~31) | ((j + 8 * (j >> 5)) & 31);  // physical slot for column j
    float* wptr = pbuf + pj;

    // init: state = exp(y_pred[b,0,:] * mask[b,0])  (parity 0)
    if (c4 == 0) wptr[0] = __expf(yp_b[j] * m_b[0]);
    __syncthreads();

    // depth-4 prefetch of x_t rows and mask
    float xpre[4], mpre[4];
    #pragma unroll
    for (int k = 0; k < 4; ++k) {
        int tt = min(1 + k, TT - 1);
        xpre[k] = yp_b[tt * CC + j];
        mpre[k] = m_b[tt];
    }

    float pending = 1.0f;   // lazy renorm scale, applied at next write
    float log_acc = 0.0f;   // accumulated log of renorm factors

    for (int g = 0; g < 128; ++g) {
        #pragma unroll
        for (int k = 0; k < 4; ++k) {
            const int t = 4 * g + k + 1;
            if (t < TT) {                       // block-uniform guard
                const int rq = k & 1;           // read parity ((t-1)&1)
                const int wq = rq ^ 1;          // write parity (t&1)
                float xv = xpre[k];
                float mv = mpre[k];
                int tp = min(t + 4, TT - 1);
                xpre[k] = yp_b[tp * CC + j];
                mpre[k] = m_b[tp];

                float dot = 0.f;
                #pragma unroll
                for (int kk = 0; kk < 8; ++kk) {
                    float4 p = *(pp[kk] + rq * 32);   // static 512B parity offset
                    dot = fmaf(p.x, Ereg[4 * kk + 0], dot);
                    dot = fmaf(p.y, Ereg[4 * kk + 1], dot);
                    dot = fmaf(p.z, Ereg[4 * kk + 2], dot);
                    dot = fmaf(p.w, Ereg[4 * kk + 3], dot);
                }
                dot += __shfl_xor(dot, 1);
                dot += __shfl_xor(dot, 2);

                if (c4 == 0) {
                    float val = (mv > 0.f) ? dot * __expf(xv) : wptr[rq * CC];
                    wptr[wq * CC] = val * pending;
                }
                pending = 1.0f;
                __syncthreads();

                if (k == 3) {  // t % 4 == 0: renorm off the just-written buffer
                    if (tid < 64) {
                        float mx = fmaxf(pbuf[wq * CC + tid], pbuf[wq * CC + tid + 64]);
                        #pragma unroll
                        for (int s = 32; s >= 1; s >>= 1)
                            mx = fmaxf(mx, __shfl_xor(mx, s));
                        if (tid == 0) red_s = mx;
                    }
                    __syncthreads();
                    float smax = red_s;
                    pending = 1.0f / smax;
                    log_acc += __logf(smax);
                }
            }
        }
    }

    // last write was t=511 -> parity 1. all_paths = log(sum) + log_acc.
    if (tid < 64) {
        float sm = pbuf[CC + tid] + pbuf[CC + tid + 64];
        #pragma unroll
        for (int s = 32; s >= 1; s >>= 1)
            sm += __shfl_xor(sm, s);
        if (tid == 0)
            out[b] = __logf(sm) + log_acc + out[b];   // out[b] holds -real_path
    }
}

// ---------------------------------------------------------------------------
extern "C" void kernel_launch(void* const* d_in, const int* in_sizes, int n_in,
                              void* d_out, int out_size, void* d_ws, size_t ws_size,
                              hipStream_t stream) {
    (void)in_sizes; (void)n_in; (void)out_size; (void)d_ws; (void)ws_size;
    const float* y_true = (const float*)d_in[0];
    const float* y_pred = (const float*)d_in[1];
    const float* mask   = (const float*)d_in[2];
    const float* trans  = (const float*)d_in[3];
    float* out = (float*)d_out;

    hipMemsetAsync(out, 0, BB * sizeof(float), stream);
    crf_real_path<<<dim3(BB, 8), 256, 0, stream>>>(y_true, y_pred, mask, trans, out);
    crf_forward<<<dim3(BB), 512, 0, stream>>>(y_pred, mask, trans, out);
}